// Round 2
// baseline (61.130 us; speedup 1.0000x reference)
//
#include <hip/hip_runtime.h>

// YOLO v1 loss, fp32. preds/labels: [B, 7, 7, 30] fp32. Output: scalar fp32.
// Per-wave LDS staging: coalesced flat float2 loads -> LDS -> per-cell reads.

#define LAMBDA_COORD 5.0f
#define LAMBDA_NOOBJ 0.5f

#define CELLS_PER_WAVE 64
#define FLOATS_PER_CELL 30
#define WAVE_FLOATS (CELLS_PER_WAVE * FLOATS_PER_CELL)   // 1920
#define WAVE_F2 (WAVE_FLOATS / 2)                        // 960
#define F2_PER_LANE (WAVE_F2 / 64)                       // 15

__device__ __forceinline__ float iou_xywh(const float* b1, const float* b2) {
    float b1x1 = b1[0] - b1[2] * 0.5f;
    float b1y1 = b1[1] - b1[3] * 0.5f;
    float b1x2 = b1[0] + b1[2] * 0.5f;
    float b1y2 = b1[1] + b1[3] * 0.5f;
    float b2x1 = b2[0] - b2[2] * 0.5f;
    float b2y1 = b2[1] - b2[3] * 0.5f;
    float b2x2 = b2[0] + b2[2] * 0.5f;
    float b2y2 = b2[1] + b2[3] * 0.5f;
    float iw = fmaxf(fminf(b1x2, b2x2) - fmaxf(b1x1, b2x1), 0.0f);
    float ih = fmaxf(fminf(b1y2, b2y2) - fmaxf(b1y1, b2y1), 0.0f);
    float inter = iw * ih;
    float area1 = (b1x2 - b1x1) * (b1y2 - b1y1);
    float area2 = (b2x2 - b2x1) * (b2y2 - b2y1);
    return inter / (area1 + area2 - inter + 1e-10f);
}

__device__ __forceinline__ float block_reduce_sum(float v, float* smem) {
    #pragma unroll
    for (int off = 32; off > 0; off >>= 1)
        v += __shfl_down(v, off, 64);
    int lane = threadIdx.x & 63;
    int wid  = threadIdx.x >> 6;
    if (lane == 0) smem[wid] = v;
    __syncthreads();
    float total = 0.0f;
    if (threadIdx.x == 0) {
        int nw = blockDim.x >> 6;
        for (int i = 0; i < nw; ++i) total += smem[i];
    }
    return total;  // valid only on thread 0
}

__global__ void __launch_bounds__(256) yolo_partial(
        const float* __restrict__ preds,
        const float* __restrict__ labels,
        float* __restrict__ partial,
        int ncells) {
    // per-wave private staging regions: [wave][{pred,label}][1920 floats]
    __shared__ float lds[4][2][WAVE_FLOATS];
    __shared__ float smem[4];

    int lane = threadIdx.x & 63;
    int wid  = threadIdx.x >> 6;

    int nchunks = (ncells + 255) / 256;   // cells per block-chunk = 256
    float acc = 0.0f;

    for (int chunk = blockIdx.x; chunk < nchunks; chunk += gridDim.x) {
        int cell0 = chunk * 256 + wid * CELLS_PER_WAVE;  // first cell of this wave
        int wvalid = ncells - cell0;                     // cells valid for this wave
        if (wvalid <= 0) continue;
        if (wvalid > CELLS_PER_WAVE) wvalid = CELLS_PER_WAVE;
        int f2valid = wvalid * (FLOATS_PER_CELL / 2);    // valid float2 count

        const float2* gp = reinterpret_cast<const float2*>(preds)  + (size_t)cell0 * 15;
        const float2* gl = reinterpret_cast<const float2*>(labels) + (size_t)cell0 * 15;

        // coalesced flat staging: lane l handles float2 indices l + i*64
        #pragma unroll
        for (int i = 0; i < F2_PER_LANE; ++i) {
            int fi = lane + i * 64;
            float2 vp = (fi < f2valid) ? gp[fi] : make_float2(0.f, 0.f);
            float2 vl = (fi < f2valid) ? gl[fi] : make_float2(0.f, 0.f);
            *reinterpret_cast<float2*>(&lds[wid][0][fi * 2]) = vp;
            *reinterpret_cast<float2*>(&lds[wid][1][fi * 2]) = vl;
        }
        // wave-synchronous: same wave wrote, same wave reads (compiler adds lgkmcnt)

        if (lane < wvalid) {
            float p[30], l[30];
            #pragma unroll
            for (int i = 0; i < 15; ++i) {
                float2 tp = *reinterpret_cast<const float2*>(&lds[wid][0][lane * 30 + 2 * i]);
                float2 tl = *reinterpret_cast<const float2*>(&lds[wid][1][lane * 30 + 2 * i]);
                p[2 * i]     = tp.x;
                p[2 * i + 1] = tp.y;
                l[2 * i]     = tl.x;
                l[2 * i + 1] = tl.y;
            }

            bool obj  = (l[4] == 1.0f);
            float iou1 = iou_xywh(p + 0, l + 0);
            float iou2 = iou_xywh(p + 5, l + 0);
            bool box1 = (iou1 > iou2);

            float dx1 = l[0] - p[0], dy1 = l[1] - p[1];
            float xy1 = dx1 * dx1 + dy1 * dy1;
            float dx2 = l[5] - p[5], dy2 = l[6] - p[6];
            float xy2 = dx2 * dx2 + dy2 * dy2;

            float dw1 = sqrtf(l[2]) - sqrtf(p[2]);
            float dh1 = sqrtf(l[3]) - sqrtf(p[3]);
            float wh1 = dw1 * dw1 + dh1 * dh1;
            float dw2 = sqrtf(l[7]) - sqrtf(p[7]);
            float dh2 = sqrtf(l[8]) - sqrtf(p[8]);
            float wh2 = dw2 * dw2 + dh2 * dh2;

            float dc1 = l[4] - p[4];
            float conf1 = dc1 * dc1;
            float dc2 = l[9] - p[9];
            float conf2 = dc2 * dc2;

            float cls = 0.0f;
            #pragma unroll
            for (int k = 10; k < 30; ++k) {
                float d = l[k] - p[k];
                cls = fmaf(d, d, cls);
            }

            float cell;
            if (obj) {
                float xy  = box1 ? xy1 : xy2;
                float wh  = box1 ? wh1 : wh2;
                float cf  = box1 ? conf1 : conf2;
                float no  = box1 ? p[9] * p[9] : p[4] * p[4];
                cell = LAMBDA_COORD * (xy + wh) + cf + LAMBDA_NOOBJ * no + cls;
            } else {
                cell = LAMBDA_NOOBJ * (p[4] * p[4] + p[9] * p[9]);
            }
            acc += cell;
        }
    }

    float bsum = block_reduce_sum(acc, smem);
    if (threadIdx.x == 0) partial[blockIdx.x] = bsum;
}

__global__ void __launch_bounds__(256) yolo_finalize(
        const float* __restrict__ partial,
        int npartial,
        float* __restrict__ out,
        float inv_batch) {
    __shared__ float smem[4];
    float acc = 0.0f;
    for (int i = threadIdx.x; i < npartial; i += blockDim.x)
        acc += partial[i];
    float total = block_reduce_sum(acc, smem);
    if (threadIdx.x == 0) out[0] = total * inv_batch;
}

extern "C" void kernel_launch(void* const* d_in, const int* in_sizes, int n_in,
                              void* d_out, int out_size, void* d_ws, size_t ws_size,
                              hipStream_t stream) {
    const float* preds  = (const float*)d_in[0];
    const float* labels = (const float*)d_in[1];
    float* out = (float*)d_out;
    float* partial = (float*)d_ws;

    int ncells = in_sizes[0] / 30;           // B * 7 * 7
    int batch  = ncells / 49;                // B
    float inv_batch = 1.0f / (float)batch;

    int nchunks = (ncells + 255) / 256;      // 3136 at B=16384
    int grid = nchunks;
    int maxblocks = (int)(ws_size / sizeof(float));
    if (grid > maxblocks) grid = maxblocks;  // grid-stride covers the rest
    if (grid < 1) grid = 1;

    yolo_partial<<<grid, 256, 0, stream>>>(preds, labels, partial, ncells);
    yolo_finalize<<<1, 256, 0, stream>>>(partial, grid, out, inv_batch);
}

// Round 3
// 45.499 us; speedup vs baseline: 1.3435x; 1.3435x over previous
//
#include <hip/hip_runtime.h>

// YOLO v1 loss, fp32. preds/labels: [B, 7, 7, 30] fp32. Output: scalar fp32.
// Block stages 256 cells through ONE 30 KiB LDS buffer in two phases
// (preds, then labels) -> coalesced float4 global loads, high occupancy.

#define LAMBDA_COORD 5.0f
#define LAMBDA_NOOBJ 0.5f

#define CHUNK_CELLS 256
#define CHUNK_FLOATS (CHUNK_CELLS * 30)   // 7680 floats = 30720 B
#define CHUNK_F4 (CHUNK_FLOATS / 4)       // 1920 float4

__device__ __forceinline__ float iou_xywh(const float* b1, const float* b2) {
    float b1x1 = b1[0] - b1[2] * 0.5f;
    float b1y1 = b1[1] - b1[3] * 0.5f;
    float b1x2 = b1[0] + b1[2] * 0.5f;
    float b1y2 = b1[1] + b1[3] * 0.5f;
    float b2x1 = b2[0] - b2[2] * 0.5f;
    float b2y1 = b2[1] - b2[3] * 0.5f;
    float b2x2 = b2[0] + b2[2] * 0.5f;
    float b2y2 = b2[1] + b2[3] * 0.5f;
    float iw = fmaxf(fminf(b1x2, b2x2) - fmaxf(b1x1, b2x1), 0.0f);
    float ih = fmaxf(fminf(b1y2, b2y2) - fmaxf(b1y1, b2y1), 0.0f);
    float inter = iw * ih;
    float area1 = (b1x2 - b1x1) * (b1y2 - b1y1);
    float area2 = (b2x2 - b2x1) * (b2y2 - b2y1);
    return inter / (area1 + area2 - inter + 1e-10f);
}

__device__ __forceinline__ float block_reduce_sum(float v, float* smem) {
    #pragma unroll
    for (int off = 32; off > 0; off >>= 1)
        v += __shfl_down(v, off, 64);
    int lane = threadIdx.x & 63;
    int wid  = threadIdx.x >> 6;
    if (lane == 0) smem[wid] = v;
    __syncthreads();
    float total = 0.0f;
    if (threadIdx.x == 0) {
        int nw = blockDim.x >> 6;
        for (int i = 0; i < nw; ++i) total += smem[i];
    }
    return total;  // valid only on thread 0
}

// Coalesced float4 staging of up to CHUNK_FLOATS floats into LDS.
__device__ __forceinline__ void stage_chunk(const float* __restrict__ g,
                                            float* __restrict__ s,
                                            int nfl, int tid) {
    const float4* g4 = reinterpret_cast<const float4*>(g);
    #pragma unroll
    for (int i = 0; i < 8; ++i) {              // ceil(1920/256) = 8 iters
        int fi = tid + 256 * i;                // float4 index in chunk
        int f0 = fi * 4;
        if (f0 + 3 < nfl) {
            *reinterpret_cast<float4*>(&s[f0]) = g4[fi];
        } else if (f0 < nfl) {                 // ragged tail (last chunk only)
            for (int c = 0; c < 4; ++c)
                if (f0 + c < nfl) s[f0 + c] = g[f0 + c];
        }
    }
}

__global__ void __launch_bounds__(256) yolo_partial(
        const float* __restrict__ preds,
        const float* __restrict__ labels,
        float* __restrict__ partial,
        int ncells) {
    __shared__ float buf[CHUNK_FLOATS];        // 30720 B, reused for both arrays
    __shared__ float smem[4];

    int tid = threadIdx.x;
    int nchunks = (ncells + CHUNK_CELLS - 1) / CHUNK_CELLS;
    float acc = 0.0f;

    for (int chunk = blockIdx.x; chunk < nchunks; chunk += gridDim.x) {
        size_t fbase = (size_t)chunk * CHUNK_FLOATS;         // float offset
        int cells_here = ncells - chunk * CHUNK_CELLS;
        if (cells_here > CHUNK_CELLS) cells_here = CHUNK_CELLS;
        int nfl = cells_here * 30;
        bool valid = (tid < cells_here);

        float p[30], l[30];

        // ---- phase 1: preds ----
        __syncthreads();                       // previous iteration done reading
        stage_chunk(preds + fbase, buf, nfl, tid);
        __syncthreads();
        if (valid) {
            const float2* b2 = reinterpret_cast<const float2*>(buf);
            #pragma unroll
            for (int i = 0; i < 15; ++i) {
                float2 t = b2[tid * 15 + i];
                p[2 * i]     = t.x;
                p[2 * i + 1] = t.y;
            }
        }

        // ---- phase 2: labels (reuse same LDS buffer) ----
        __syncthreads();                       // all pred reads done
        stage_chunk(labels + fbase, buf, nfl, tid);
        __syncthreads();
        if (valid) {
            const float2* b2 = reinterpret_cast<const float2*>(buf);
            #pragma unroll
            for (int i = 0; i < 15; ++i) {
                float2 t = b2[tid * 15 + i];
                l[2 * i]     = t.x;
                l[2 * i + 1] = t.y;
            }

            bool obj  = (l[4] == 1.0f);
            float iou1 = iou_xywh(p + 0, l + 0);
            float iou2 = iou_xywh(p + 5, l + 0);
            bool box1 = (iou1 > iou2);

            float dx1 = l[0] - p[0], dy1 = l[1] - p[1];
            float xy1 = dx1 * dx1 + dy1 * dy1;
            float dx2 = l[5] - p[5], dy2 = l[6] - p[6];
            float xy2 = dx2 * dx2 + dy2 * dy2;

            float dw1 = sqrtf(l[2]) - sqrtf(p[2]);
            float dh1 = sqrtf(l[3]) - sqrtf(p[3]);
            float wh1 = dw1 * dw1 + dh1 * dh1;
            float dw2 = sqrtf(l[7]) - sqrtf(p[7]);
            float dh2 = sqrtf(l[8]) - sqrtf(p[8]);
            float wh2 = dw2 * dw2 + dh2 * dh2;

            float dc1 = l[4] - p[4];
            float conf1 = dc1 * dc1;
            float dc2 = l[9] - p[9];
            float conf2 = dc2 * dc2;

            float cls = 0.0f;
            #pragma unroll
            for (int k = 10; k < 30; ++k) {
                float d = l[k] - p[k];
                cls = fmaf(d, d, cls);
            }

            float cell;
            if (obj) {
                float xy  = box1 ? xy1 : xy2;
                float wh  = box1 ? wh1 : wh2;
                float cf  = box1 ? conf1 : conf2;
                float no  = box1 ? p[9] * p[9] : p[4] * p[4];
                cell = LAMBDA_COORD * (xy + wh) + cf + LAMBDA_NOOBJ * no + cls;
            } else {
                cell = LAMBDA_NOOBJ * (p[4] * p[4] + p[9] * p[9]);
            }
            acc += cell;
        }
    }

    float bsum = block_reduce_sum(acc, smem);
    if (threadIdx.x == 0) partial[blockIdx.x] = bsum;
}

__global__ void __launch_bounds__(256) yolo_finalize(
        const float* __restrict__ partial,
        int npartial,
        float* __restrict__ out,
        float inv_batch) {
    __shared__ float smem[4];
    float acc = 0.0f;
    for (int i = threadIdx.x; i < npartial; i += blockDim.x)
        acc += partial[i];
    float total = block_reduce_sum(acc, smem);
    if (threadIdx.x == 0) out[0] = total * inv_batch;
}

extern "C" void kernel_launch(void* const* d_in, const int* in_sizes, int n_in,
                              void* d_out, int out_size, void* d_ws, size_t ws_size,
                              hipStream_t stream) {
    const float* preds  = (const float*)d_in[0];
    const float* labels = (const float*)d_in[1];
    float* out = (float*)d_out;
    float* partial = (float*)d_ws;

    int ncells = in_sizes[0] / 30;           // B * 7 * 7
    int batch  = ncells / 49;                // B
    float inv_batch = 1.0f / (float)batch;

    int nchunks = (ncells + CHUNK_CELLS - 1) / CHUNK_CELLS;  // 3136 at B=16384
    int grid = nchunks;
    int maxblocks = (int)(ws_size / sizeof(float));
    if (grid > maxblocks) grid = maxblocks;  // grid-stride covers the rest
    if (grid < 1) grid = 1;

    yolo_partial<<<grid, 256, 0, stream>>>(preds, labels, partial, ncells);
    yolo_finalize<<<1, 256, 0, stream>>>(partial, grid, out, inv_batch);
}